// Round 1
// baseline (251.762 us; speedup 1.0000x reference)
//
#include <hip/hip_runtime.h>

#define B_ 16
#define C_ 3
#define H_ 384
#define W_ 1280
#define HW_ (H_*W_)
#define EPS_ 1e-7f

// Tiling: each block = 256 threads covering a 256-col x 2-row tile.
// Vertical adjacency (same thread handles rows i, i+1) gives L1-level reuse
// of the shared bilinear source row; XCD-swizzled dispatch makes consecutive
// row-tiles land on the same XCD so the tile-boundary row is an L2 hit.
#define COLS_ 256
#define ROWS_ 2
#define BANDS_ (W_/COLS_)              // 5
#define RTILES_ (H_/ROWS_)             // 192
#define NBLK_ (BANDS_*RTILES_*B_)      // 15360 (divisible by 8 -> simple swizzle is bijective)
#define NXCD_ 8

typedef float v2f __attribute__((ext_vector_type(2)));

// 8-byte load at 4-byte alignment — single global_load_dwordx2 covering both
// x-taps of one source row.
__device__ __forceinline__ v2f load2(const float* p) {
  v2f r;
  __builtin_memcpy(&r, p, 8);
  return r;
}

__device__ __forceinline__ void mat3mul(const float* A, const float* Bm, float* C) {
  #pragma unroll
  for (int i = 0; i < 3; i++)
    #pragma unroll
    for (int j = 0; j < 3; j++)
      C[i*3+j] = A[i*3+0]*Bm[0*3+j] + A[i*3+1]*Bm[1*3+j] + A[i*3+2]*Bm[2*3+j];
}

// M = K * R * inv(K), T = K * t for batch b.
__device__ void compute_MT(const float* __restrict__ pose,
                           const float* __restrict__ intr,
                           int b, float* M, float* T)
{
  float K[9];
  #pragma unroll
  for (int i = 0; i < 9; i++) K[i] = intr[b*9 + i];
  float aa0 = pose[b*6 + 0], aa1 = pose[b*6 + 1], aa2 = pose[b*6 + 2];
  float t0  = pose[b*6 + 3], t1  = pose[b*6 + 4], t2  = pose[b*6 + 5];

  float theta = sqrtf(aa0*aa0 + aa1*aa1 + aa2*aa2);
  float invn  = 1.0f / (theta + EPS_);
  float x = aa0*invn, y = aa1*invn, z = aa2*invn;
  float c = cosf(theta), s = sinf(theta), t = 1.0f - c;
  float R[9] = {
    t*x*x + c,   t*x*y - s*z, t*z*x + s*y,
    t*x*y + s*z, t*y*y + c,   t*y*z - s*x,
    t*z*x - s*y, t*y*z + s*x, t*z*z + c
  };

  float a = K[0], bb = K[1], cc = K[2];
  float d = K[3], e  = K[4], f  = K[5];
  float g = K[6], h  = K[7], ii = K[8];
  float A0 = e*ii - f*h, A1 = f*g - d*ii, A2 = d*h - e*g;
  float id = 1.0f / (a*A0 + bb*A1 + cc*A2);
  float iK[9] = {
    A0*id, (cc*h - bb*ii)*id, (bb*f - cc*e)*id,
    A1*id, (a*ii - cc*g)*id,  (cc*d - a*f)*id,
    A2*id, (bb*g - a*h)*id,   (a*e  - bb*d)*id
  };

  float KR[9];
  mat3mul(K, R, KR);
  mat3mul(KR, iK, M);
  T[0] = K[0]*t0 + K[1]*t1 + K[2]*t2;
  T[1] = K[3]*t0 + K[4]*t1 + K[5]*t2;
  T[2] = K[6]*t0 + K[7]*t1 + K[8]*t2;
}

__global__ __launch_bounds__(256) void warp_kernel(
    const float* __restrict__ src,
    const float* __restrict__ depth,
    const float* __restrict__ pose,
    const float* __restrict__ intr,
    float* __restrict__ out)
{
  __shared__ float sp[12];

  // XCD-aware bijective swizzle: HW round-robins blockIdx.x across the 8 XCDs.
  // Map so each XCD owns a contiguous chunk of work ids; decode with row-tile
  // FASTEST so consecutive dispatch slots on one XCD are vertically adjacent
  // tiles of the same column band -> boundary source rows hit that XCD's L2.
  int l = blockIdx.x;
  int w = (l & (NXCD_-1)) * (NBLK_/NXCD_) + (l >> 3);
  int rt   = w % RTILES_;
  int tmp  = w / RTILES_;
  int band = tmp % BANDS_;
  int b    = tmp / BANDS_;

  if (threadIdx.x == 0) {
    float M[9], T[3];
    compute_MT(pose, intr, b, M, T);
    #pragma unroll
    for (int i = 0; i < 9; i++) sp[i] = M[i];
    #pragma unroll
    for (int i = 0; i < 3; i++) sp[9 + i] = T[i];
  }
  __syncthreads();
  float m00 = sp[0], m01 = sp[1], m02 = sp[2];
  float m10 = sp[3], m11 = sp[4], m12 = sp[5];
  float m20 = sp[6], m21 = sp[7], m22 = sp[8];
  float T0  = sp[9], T1  = sp[10], T2 = sp[11];

  int j  = band * COLS_ + threadIdx.x;
  int i0 = rt * ROWS_;
  float xf = (float)j;

  // x-only part of the projective transform (row-invariant for this thread)
  float ax = m00*xf + m02;
  float ay = m10*xf + m12;
  float az = m20*xf + m22;

  size_t sb = (size_t)b * C_ * HW_;
  const float* s0p = src + sb;
  const float* s1p = s0p + HW_;
  const float* s2p = s1p + HW_;

  // depth is streamed exactly once: nontemporal so it doesn't evict src rows
  const float* dp = depth + (size_t)b * HW_ + (size_t)i0 * W_ + j;
  float dv[ROWS_];
  #pragma unroll
  for (int r = 0; r < ROWS_; r++)
    dv[r] = __builtin_nontemporal_load(dp + r * W_);

  #pragma unroll
  for (int r = 0; r < ROWS_; r++) {
    int i = i0 + r;
    float yf = (float)i;
    float d  = dv[r];

    float cx = (ax + m01*yf)*d + T0;
    float cy = (ay + m11*yf)*d + T1;
    float cz = (az + m21*yf)*d + T2;
    float inv = 1.0f / (cz + EPS_);
    float px = cx * inv;
    float py = cy * inv;

    float x0f = floorf(px), y0f = floorf(py);
    float x1f = x0f + 1.0f, y1f = y0f + 1.0f;
    float wx1 = px - x0f, wx0 = 1.0f - wx1;
    float wy1 = py - y0f, wy0 = 1.0f - wy1;

    float mx0 = (x0f >= 0.0f && x0f <= (float)(W_-1)) ? 1.0f : 0.0f;
    float mx1 = (x1f >= 0.0f && x1f <= (float)(W_-1)) ? 1.0f : 0.0f;
    float my0 = (y0f >= 0.0f && y0f <= (float)(H_-1)) ? 1.0f : 0.0f;
    float my1 = (y1f >= 0.0f && y1f <= (float)(H_-1)) ? 1.0f : 0.0f;

    int xc0 = (int)fminf(fmaxf(x0f, 0.0f), (float)(W_-1));
    int xc1 = (int)fminf(fmaxf(x1f, 0.0f), (float)(W_-1));
    int yc0 = (int)fminf(fmaxf(y0f, 0.0f), (float)(H_-1));
    int yc1 = (int)fminf(fmaxf(y1f, 0.0f), (float)(H_-1));

    float w00 = wx0*wy0*mx0*my0;
    float w01 = wx1*wy0*mx1*my0;
    float w10 = wx0*wy1*mx0*my1;
    float w11 = wx1*wy1*mx1*my1;

    // x-pair merge: one 8B load covers both taps of a row.
    // base = min(xc0, W-2); xc0,xc1 ∈ {base, base+1} in ALL clamp cases.
    int base = xc0 < (W_-2) ? xc0 : (W_-2);
    bool sl0 = (xc0 == base);
    bool sl1 = (xc1 == base + 1);
    float wax = (sl0 ? w00 : 0.0f) + (sl1 ? 0.0f : w01);
    float way = (sl0 ? 0.0f : w00) + (sl1 ? w01 : 0.0f);
    float wbx = (sl0 ? w10 : 0.0f) + (sl1 ? 0.0f : w11);
    float wby = (sl0 ? 0.0f : w10) + (sl1 ? w11 : 0.0f);

    int rb0 = yc0*W_ + base;
    int rb1 = yc1*W_ + base;

    v2f a0 = load2(s0p + rb0);
    v2f b0 = load2(s0p + rb1);
    v2f a1 = load2(s1p + rb0);
    v2f b1 = load2(s1p + rb1);
    v2f a2 = load2(s2p + rb0);
    v2f b2 = load2(s2p + rb1);

    float v0 = a0.x*wax + a0.y*way + b0.x*wbx + b0.y*wby;
    float v1 = a1.x*wax + a1.y*way + b1.x*wbx + b1.y*wby;
    float v2 = a2.x*wax + a2.y*way + b2.x*wbx + b2.y*wby;

    size_t op = (size_t)i * W_ + j;
    __builtin_nontemporal_store(v0, &out[sb + op]);
    __builtin_nontemporal_store(v1, &out[sb + HW_ + op]);
    __builtin_nontemporal_store(v2, &out[sb + 2*(size_t)HW_ + op]);
  }
}

extern "C" void kernel_launch(void* const* d_in, const int* in_sizes, int n_in,
                              void* d_out, int out_size, void* d_ws, size_t ws_size,
                              hipStream_t stream) {
  const float* src   = (const float*)d_in[0];
  const float* depth = (const float*)d_in[1];
  const float* pose  = (const float*)d_in[2];
  const float* intr  = (const float*)d_in[3];
  float* out = (float*)d_out;

  dim3 grid(NBLK_);
  warp_kernel<<<grid, 256, 0, stream>>>(src, depth, pose, intr, out);
}

// Round 2
// 244.431 us; speedup vs baseline: 1.0300x; 1.0300x over previous
//
#include <hip/hip_runtime.h>

#define B_ 16
#define C_ 3
#define H_ 384
#define W_ 1280
#define HW_ (H_*W_)
#define EPS_ 1e-7f

// Tiling: each block = 256 threads covering a 256-col x 2-row tile.
// Vertical adjacency (same thread handles rows i, i+1) gives L1-level reuse
// of the shared bilinear source row; XCD-swizzled dispatch makes consecutive
// row-tiles land on the same XCD so the tile-boundary row is an L2 hit.
// R1 lesson: FETCH 284->57 MB (src L3-resident) but latency-bound at VGPR=20.
// This version straight-lines both rows and batches all 12 gathers for MLP.
#define COLS_ 256
#define ROWS_ 2
#define BANDS_ (W_/COLS_)              // 5
#define RTILES_ (H_/ROWS_)             // 192
#define NBLK_ (BANDS_*RTILES_*B_)      // 15360 (divisible by 8 -> swizzle bijective)
#define NXCD_ 8

typedef float v2f __attribute__((ext_vector_type(2)));

// 8-byte load at 4-byte alignment — single global_load_dwordx2 covering both
// x-taps of one source row.
__device__ __forceinline__ v2f load2(const float* p) {
  v2f r;
  __builtin_memcpy(&r, p, 8);
  return r;
}

__device__ __forceinline__ void mat3mul(const float* A, const float* Bm, float* C) {
  #pragma unroll
  for (int i = 0; i < 3; i++)
    #pragma unroll
    for (int j = 0; j < 3; j++)
      C[i*3+j] = A[i*3+0]*Bm[0*3+j] + A[i*3+1]*Bm[1*3+j] + A[i*3+2]*Bm[2*3+j];
}

// M = K * R * inv(K), T = K * t for batch b.
__device__ void compute_MT(const float* __restrict__ pose,
                           const float* __restrict__ intr,
                           int b, float* M, float* T)
{
  float K[9];
  #pragma unroll
  for (int i = 0; i < 9; i++) K[i] = intr[b*9 + i];
  float aa0 = pose[b*6 + 0], aa1 = pose[b*6 + 1], aa2 = pose[b*6 + 2];
  float t0  = pose[b*6 + 3], t1  = pose[b*6 + 4], t2  = pose[b*6 + 5];

  float theta = sqrtf(aa0*aa0 + aa1*aa1 + aa2*aa2);
  float invn  = 1.0f / (theta + EPS_);
  float x = aa0*invn, y = aa1*invn, z = aa2*invn;
  float c = cosf(theta), s = sinf(theta), t = 1.0f - c;
  float R[9] = {
    t*x*x + c,   t*x*y - s*z, t*z*x + s*y,
    t*x*y + s*z, t*y*y + c,   t*y*z - s*x,
    t*z*x - s*y, t*y*z + s*x, t*z*z + c
  };

  float a = K[0], bb = K[1], cc = K[2];
  float d = K[3], e  = K[4], f  = K[5];
  float g = K[6], h  = K[7], ii = K[8];
  float A0 = e*ii - f*h, A1 = f*g - d*ii, A2 = d*h - e*g;
  float id = 1.0f / (a*A0 + bb*A1 + cc*A2);
  float iK[9] = {
    A0*id, (cc*h - bb*ii)*id, (bb*f - cc*e)*id,
    A1*id, (a*ii - cc*g)*id,  (cc*d - a*f)*id,
    A2*id, (bb*g - a*h)*id,   (a*e  - bb*d)*id
  };

  float KR[9];
  mat3mul(K, R, KR);
  mat3mul(KR, iK, M);
  T[0] = K[0]*t0 + K[1]*t1 + K[2]*t2;
  T[1] = K[3]*t0 + K[4]*t1 + K[5]*t2;
  T[2] = K[6]*t0 + K[7]*t1 + K[8]*t2;
}

__global__ __launch_bounds__(256) void warp_kernel(
    const float* __restrict__ src,
    const float* __restrict__ depth,
    const float* __restrict__ pose,
    const float* __restrict__ intr,
    float* __restrict__ out)
{
  __shared__ float sp[12];

  // XCD-aware bijective swizzle: consecutive dispatch slots on one XCD are
  // vertically adjacent tiles of the same column band -> boundary source rows
  // hit that XCD's L2 (R1: this cut FETCH 284->57 MB; keep).
  int l = blockIdx.x;
  int w = (l & (NXCD_-1)) * (NBLK_/NXCD_) + (l >> 3);
  int rt   = w % RTILES_;
  int tmp  = w / RTILES_;
  int band = tmp % BANDS_;
  int b    = tmp / BANDS_;

  int j  = band * COLS_ + threadIdx.x;
  int i0 = rt * ROWS_;

  // Issue depth loads BEFORE the barrier: latency hides under M/T compute.
  // No nontemporal flag: depth should stay L3-resident across dispatches.
  const float* dp = depth + (size_t)b * HW_ + (size_t)i0 * W_ + j;
  float d0 = dp[0];
  float d1 = dp[W_];

  if (threadIdx.x == 0) {
    float M[9], T[3];
    compute_MT(pose, intr, b, M, T);
    #pragma unroll
    for (int i = 0; i < 9; i++) sp[i] = M[i];
    #pragma unroll
    for (int i = 0; i < 3; i++) sp[9 + i] = T[i];
  }
  __syncthreads();
  float m00 = sp[0], m01 = sp[1], m02 = sp[2];
  float m10 = sp[3], m11 = sp[4], m12 = sp[5];
  float m20 = sp[6], m21 = sp[7], m22 = sp[8];
  float T0  = sp[9], T1  = sp[10], T2 = sp[11];

  float xf = (float)j;
  // x-only part of the projective transform (row-invariant for this thread)
  float ax = m00*xf + m02;
  float ay = m10*xf + m12;
  float az = m20*xf + m22;

  size_t sb = (size_t)b * C_ * HW_;
  const float* s0p = src + sb;
  const float* s1p = s0p + HW_;
  const float* s2p = s1p + HW_;

  // ---- Row 0: projective math -> weights + offsets (no loads yet) ----
  float yf0 = (float)i0;
  float cz0 = (az + m21*yf0)*d0 + T2;
  float inv0 = 1.0f / (cz0 + EPS_);
  float px0 = ((ax + m01*yf0)*d0 + T0) * inv0;
  float py0 = ((ay + m11*yf0)*d0 + T1) * inv0;

  float x0f_0 = floorf(px0), y0f_0 = floorf(py0);
  float wx1_0 = px0 - x0f_0, wx0_0 = 1.0f - wx1_0;
  float wy1_0 = py0 - y0f_0, wy0_0 = 1.0f - wy1_0;
  float mx0_0 = (x0f_0 >= 0.0f && x0f_0 <= (float)(W_-1)) ? 1.0f : 0.0f;
  float mx1_0 = (x0f_0+1.0f >= 0.0f && x0f_0+1.0f <= (float)(W_-1)) ? 1.0f : 0.0f;
  float my0_0 = (y0f_0 >= 0.0f && y0f_0 <= (float)(H_-1)) ? 1.0f : 0.0f;
  float my1_0 = (y0f_0+1.0f >= 0.0f && y0f_0+1.0f <= (float)(H_-1)) ? 1.0f : 0.0f;
  int xc0_0 = (int)fminf(fmaxf(x0f_0, 0.0f), (float)(W_-1));
  int xc1_0 = (int)fminf(fmaxf(x0f_0+1.0f, 0.0f), (float)(W_-1));
  int yc0_0 = (int)fminf(fmaxf(y0f_0, 0.0f), (float)(H_-1));
  int yc1_0 = (int)fminf(fmaxf(y0f_0+1.0f, 0.0f), (float)(H_-1));
  float w00_0 = wx0_0*wy0_0*mx0_0*my0_0;
  float w01_0 = wx1_0*wy0_0*mx1_0*my0_0;
  float w10_0 = wx0_0*wy1_0*mx0_0*my1_0;
  float w11_0 = wx1_0*wy1_0*mx1_0*my1_0;
  // x-pair merge: base = min(xc0, W-2); xc0,xc1 ∈ {base, base+1} in all cases.
  int base_0 = xc0_0 < (W_-2) ? xc0_0 : (W_-2);
  bool s0_0 = (xc0_0 == base_0);
  bool s1_0 = (xc1_0 == base_0 + 1);
  float wax0 = (s0_0 ? w00_0 : 0.0f) + (s1_0 ? 0.0f : w01_0);
  float way0 = (s0_0 ? 0.0f : w00_0) + (s1_0 ? w01_0 : 0.0f);
  float wbx0 = (s0_0 ? w10_0 : 0.0f) + (s1_0 ? 0.0f : w11_0);
  float wby0 = (s0_0 ? 0.0f : w10_0) + (s1_0 ? w11_0 : 0.0f);
  int rb0_0 = yc0_0*W_ + base_0;
  int rb1_0 = yc1_0*W_ + base_0;

  // ---- Row 1: same, straight-lined ----
  float yf1 = (float)(i0 + 1);
  float cz1 = (az + m21*yf1)*d1 + T2;
  float inv1 = 1.0f / (cz1 + EPS_);
  float px1 = ((ax + m01*yf1)*d1 + T0) * inv1;
  float py1 = ((ay + m11*yf1)*d1 + T1) * inv1;

  float x0f_1 = floorf(px1), y0f_1 = floorf(py1);
  float wx1_1 = px1 - x0f_1, wx0_1 = 1.0f - wx1_1;
  float wy1_1 = py1 - y0f_1, wy0_1 = 1.0f - wy1_1;
  float mx0_1 = (x0f_1 >= 0.0f && x0f_1 <= (float)(W_-1)) ? 1.0f : 0.0f;
  float mx1_1 = (x0f_1+1.0f >= 0.0f && x0f_1+1.0f <= (float)(W_-1)) ? 1.0f : 0.0f;
  float my0_1 = (y0f_1 >= 0.0f && y0f_1 <= (float)(H_-1)) ? 1.0f : 0.0f;
  float my1_1 = (y0f_1+1.0f >= 0.0f && y0f_1+1.0f <= (float)(H_-1)) ? 1.0f : 0.0f;
  int xc0_1 = (int)fminf(fmaxf(x0f_1, 0.0f), (float)(W_-1));
  int xc1_1 = (int)fminf(fmaxf(x0f_1+1.0f, 0.0f), (float)(W_-1));
  int yc0_1 = (int)fminf(fmaxf(y0f_1, 0.0f), (float)(H_-1));
  int yc1_1 = (int)fminf(fmaxf(y0f_1+1.0f, 0.0f), (float)(H_-1));
  float w00_1 = wx0_1*wy0_1*mx0_1*my0_1;
  float w01_1 = wx1_1*wy0_1*mx1_1*my0_1;
  float w10_1 = wx0_1*wy1_1*mx0_1*my1_1;
  float w11_1 = wx1_1*wy1_1*mx1_1*my1_1;
  int base_1 = xc0_1 < (W_-2) ? xc0_1 : (W_-2);
  bool s0_1 = (xc0_1 == base_1);
  bool s1_1 = (xc1_1 == base_1 + 1);
  float wax1 = (s0_1 ? w00_1 : 0.0f) + (s1_1 ? 0.0f : w01_1);
  float way1 = (s0_1 ? 0.0f : w00_1) + (s1_1 ? w01_1 : 0.0f);
  float wbx1 = (s0_1 ? w10_1 : 0.0f) + (s1_1 ? 0.0f : w11_1);
  float wby1 = (s0_1 ? 0.0f : w10_1) + (s1_1 ? w11_1 : 0.0f);
  int rb0_1 = yc0_1*W_ + base_1;
  int rb1_1 = yc1_1*W_ + base_1;

  // ---- All 12 gathers issued back-to-back: max memory-level parallelism.
  // 12 x v2f = 24 VGPRs of results in flight; occupancy budget allows 64.
  v2f a0_0 = load2(s0p + rb0_0);
  v2f b0_0 = load2(s0p + rb1_0);
  v2f a1_0 = load2(s1p + rb0_0);
  v2f b1_0 = load2(s1p + rb1_0);
  v2f a2_0 = load2(s2p + rb0_0);
  v2f b2_0 = load2(s2p + rb1_0);
  v2f a0_1 = load2(s0p + rb0_1);
  v2f b0_1 = load2(s0p + rb1_1);
  v2f a1_1 = load2(s1p + rb0_1);
  v2f b1_1 = load2(s1p + rb1_1);
  v2f a2_1 = load2(s2p + rb0_1);
  v2f b2_1 = load2(s2p + rb1_1);

  float v0_0 = a0_0.x*wax0 + a0_0.y*way0 + b0_0.x*wbx0 + b0_0.y*wby0;
  float v1_0 = a1_0.x*wax0 + a1_0.y*way0 + b1_0.x*wbx0 + b1_0.y*wby0;
  float v2_0 = a2_0.x*wax0 + a2_0.y*way0 + b2_0.x*wbx0 + b2_0.y*wby0;
  float v0_1 = a0_1.x*wax1 + a0_1.y*way1 + b0_1.x*wbx1 + b0_1.y*wby1;
  float v1_1 = a1_1.x*wax1 + a1_1.y*way1 + b1_1.x*wbx1 + b1_1.y*wby1;
  float v2_1 = a2_1.x*wax1 + a2_1.y*way1 + b2_1.x*wbx1 + b2_1.y*wby1;

  // nt stores: output is never re-read; keeps src L3-resident (R1 evidence).
  size_t op0 = (size_t)i0 * W_ + j;
  size_t op1 = op0 + W_;
  __builtin_nontemporal_store(v0_0, &out[sb + op0]);
  __builtin_nontemporal_store(v1_0, &out[sb + HW_ + op0]);
  __builtin_nontemporal_store(v2_0, &out[sb + 2*(size_t)HW_ + op0]);
  __builtin_nontemporal_store(v0_1, &out[sb + op1]);
  __builtin_nontemporal_store(v1_1, &out[sb + HW_ + op1]);
  __builtin_nontemporal_store(v2_1, &out[sb + 2*(size_t)HW_ + op1]);
}

extern "C" void kernel_launch(void* const* d_in, const int* in_sizes, int n_in,
                              void* d_out, int out_size, void* d_ws, size_t ws_size,
                              hipStream_t stream) {
  const float* src   = (const float*)d_in[0];
  const float* depth = (const float*)d_in[1];
  const float* pose  = (const float*)d_in[2];
  const float* intr  = (const float*)d_in[3];
  float* out = (float*)d_out;

  dim3 grid(NBLK_);
  warp_kernel<<<grid, 256, 0, stream>>>(src, depth, pose, intr, out);
}

// Round 3
// 240.143 us; speedup vs baseline: 1.0484x; 1.0179x over previous
//
#include <hip/hip_runtime.h>

#define B_ 16
#define C_ 3
#define H_ 384
#define W_ 1280
#define HW_ (H_*W_)
#define EPS_ 1e-7f

// Tiling: each block = 256 threads covering a 256-col x 2-row tile.
// R1: 2-row tile + XCD swizzle cut FETCH 284->57 MB (src L3/L2-resident).
// R2: straight-lining alone didn't batch the gathers (VGPR stuck at 24 ->
//     compiler serialized loads). This version adds sched_barrier(0) between
//     the gather block and consumption to FORCE all 12 loads in flight.
#define COLS_ 256
#define ROWS_ 2
#define BANDS_ (W_/COLS_)              // 5
#define RTILES_ (H_/ROWS_)             // 192
#define NBLK_ (BANDS_*RTILES_*B_)      // 15360 (divisible by 8 -> swizzle bijective)
#define NXCD_ 8

typedef float v2f __attribute__((ext_vector_type(2)));

// 8-byte load at 4-byte alignment — single global_load_dwordx2 covering both
// x-taps of one source row.
__device__ __forceinline__ v2f load2(const float* p) {
  v2f r;
  __builtin_memcpy(&r, p, 8);
  return r;
}

__device__ __forceinline__ void mat3mul(const float* A, const float* Bm, float* C) {
  #pragma unroll
  for (int i = 0; i < 3; i++)
    #pragma unroll
    for (int j = 0; j < 3; j++)
      C[i*3+j] = A[i*3+0]*Bm[0*3+j] + A[i*3+1]*Bm[1*3+j] + A[i*3+2]*Bm[2*3+j];
}

// M = K * R * inv(K), T = K * t for batch b.
__device__ void compute_MT(const float* __restrict__ pose,
                           const float* __restrict__ intr,
                           int b, float* M, float* T)
{
  float K[9];
  #pragma unroll
  for (int i = 0; i < 9; i++) K[i] = intr[b*9 + i];
  float aa0 = pose[b*6 + 0], aa1 = pose[b*6 + 1], aa2 = pose[b*6 + 2];
  float t0  = pose[b*6 + 3], t1  = pose[b*6 + 4], t2  = pose[b*6 + 5];

  float theta = sqrtf(aa0*aa0 + aa1*aa1 + aa2*aa2);
  float invn  = 1.0f / (theta + EPS_);
  float x = aa0*invn, y = aa1*invn, z = aa2*invn;
  float c = cosf(theta), s = sinf(theta), t = 1.0f - c;
  float R[9] = {
    t*x*x + c,   t*x*y - s*z, t*z*x + s*y,
    t*x*y + s*z, t*y*y + c,   t*y*z - s*x,
    t*z*x - s*y, t*y*z + s*x, t*z*z + c
  };

  float a = K[0], bb = K[1], cc = K[2];
  float d = K[3], e  = K[4], f  = K[5];
  float g = K[6], h  = K[7], ii = K[8];
  float A0 = e*ii - f*h, A1 = f*g - d*ii, A2 = d*h - e*g;
  float id = 1.0f / (a*A0 + bb*A1 + cc*A2);
  float iK[9] = {
    A0*id, (cc*h - bb*ii)*id, (bb*f - cc*e)*id,
    A1*id, (a*ii - cc*g)*id,  (cc*d - a*f)*id,
    A2*id, (bb*g - a*h)*id,   (a*e  - bb*d)*id
  };

  float KR[9];
  mat3mul(K, R, KR);
  mat3mul(KR, iK, M);
  T[0] = K[0]*t0 + K[1]*t1 + K[2]*t2;
  T[1] = K[3]*t0 + K[4]*t1 + K[5]*t2;
  T[2] = K[6]*t0 + K[7]*t1 + K[8]*t2;
}

__global__ __launch_bounds__(256) void warp_kernel(
    const float* __restrict__ src,
    const float* __restrict__ depth,
    const float* __restrict__ pose,
    const float* __restrict__ intr,
    float* __restrict__ out)
{
  __shared__ float sp[12];

  // XCD-aware bijective swizzle: consecutive dispatch slots on one XCD are
  // vertically adjacent tiles of the same column band -> boundary source rows
  // hit that XCD's L2 (R1: this cut FETCH 284->57 MB; keep).
  int l = blockIdx.x;
  int w = (l & (NXCD_-1)) * (NBLK_/NXCD_) + (l >> 3);
  int rt   = w % RTILES_;
  int tmp  = w / RTILES_;
  int band = tmp % BANDS_;
  int b    = tmp / BANDS_;

  int j  = band * COLS_ + threadIdx.x;
  int i0 = rt * ROWS_;

  // Depth loads issued before the barrier: latency hides under M/T compute.
  const float* dp = depth + (size_t)b * HW_ + (size_t)i0 * W_ + j;
  float d0 = dp[0];
  float d1 = dp[W_];

  if (threadIdx.x == 0) {
    float M[9], T[3];
    compute_MT(pose, intr, b, M, T);
    #pragma unroll
    for (int i = 0; i < 9; i++) sp[i] = M[i];
    #pragma unroll
    for (int i = 0; i < 3; i++) sp[9 + i] = T[i];
  }
  __syncthreads();
  float m00 = sp[0], m01 = sp[1], m02 = sp[2];
  float m10 = sp[3], m11 = sp[4], m12 = sp[5];
  float m20 = sp[6], m21 = sp[7], m22 = sp[8];
  float T0  = sp[9], T1  = sp[10], T2 = sp[11];

  float xf = (float)j;
  // x-only part of the projective transform (row-invariant for this thread)
  float ax = m00*xf + m02;
  float ay = m10*xf + m12;
  float az = m20*xf + m22;

  size_t sb = (size_t)b * C_ * HW_;
  const float* s0p = src + sb;
  const float* s1p = s0p + HW_;
  const float* s2p = s1p + HW_;

  // ---- Row 0: projective math -> weights + offsets ----
  float yf0 = (float)i0;
  float cz0 = (az + m21*yf0)*d0 + T2;
  float inv0 = 1.0f / (cz0 + EPS_);
  float px0 = ((ax + m01*yf0)*d0 + T0) * inv0;
  float py0 = ((ay + m11*yf0)*d0 + T1) * inv0;

  float x0f_0 = floorf(px0), y0f_0 = floorf(py0);
  float wx1_0 = px0 - x0f_0, wx0_0 = 1.0f - wx1_0;
  float wy1_0 = py0 - y0f_0, wy0_0 = 1.0f - wy1_0;
  float mx0_0 = (x0f_0 >= 0.0f && x0f_0 <= (float)(W_-1)) ? 1.0f : 0.0f;
  float mx1_0 = (x0f_0+1.0f >= 0.0f && x0f_0+1.0f <= (float)(W_-1)) ? 1.0f : 0.0f;
  float my0_0 = (y0f_0 >= 0.0f && y0f_0 <= (float)(H_-1)) ? 1.0f : 0.0f;
  float my1_0 = (y0f_0+1.0f >= 0.0f && y0f_0+1.0f <= (float)(H_-1)) ? 1.0f : 0.0f;
  int xc0_0 = (int)fminf(fmaxf(x0f_0, 0.0f), (float)(W_-1));
  int xc1_0 = (int)fminf(fmaxf(x0f_0+1.0f, 0.0f), (float)(W_-1));
  int yc0_0 = (int)fminf(fmaxf(y0f_0, 0.0f), (float)(H_-1));
  int yc1_0 = (int)fminf(fmaxf(y0f_0+1.0f, 0.0f), (float)(H_-1));
  float w00_0 = wx0_0*wy0_0*mx0_0*my0_0;
  float w01_0 = wx1_0*wy0_0*mx1_0*my0_0;
  float w10_0 = wx0_0*wy1_0*mx0_0*my1_0;
  float w11_0 = wx1_0*wy1_0*mx1_0*my1_0;
  // x-pair merge: base = min(xc0, W-2); xc0,xc1 ∈ {base, base+1} in all cases.
  int base_0 = xc0_0 < (W_-2) ? xc0_0 : (W_-2);
  bool s0_0 = (xc0_0 == base_0);
  bool s1_0 = (xc1_0 == base_0 + 1);
  float wax0 = (s0_0 ? w00_0 : 0.0f) + (s1_0 ? 0.0f : w01_0);
  float way0 = (s0_0 ? 0.0f : w00_0) + (s1_0 ? w01_0 : 0.0f);
  float wbx0 = (s0_0 ? w10_0 : 0.0f) + (s1_0 ? 0.0f : w11_0);
  float wby0 = (s0_0 ? 0.0f : w10_0) + (s1_0 ? w11_0 : 0.0f);
  int rb0_0 = yc0_0*W_ + base_0;
  int rb1_0 = yc1_0*W_ + base_0;

  // ---- Row 1 ----
  float yf1 = (float)(i0 + 1);
  float cz1 = (az + m21*yf1)*d1 + T2;
  float inv1 = 1.0f / (cz1 + EPS_);
  float px1 = ((ax + m01*yf1)*d1 + T0) * inv1;
  float py1 = ((ay + m11*yf1)*d1 + T1) * inv1;

  float x0f_1 = floorf(px1), y0f_1 = floorf(py1);
  float wx1_1 = px1 - x0f_1, wx0_1 = 1.0f - wx1_1;
  float wy1_1 = py1 - y0f_1, wy0_1 = 1.0f - wy1_1;
  float mx0_1 = (x0f_1 >= 0.0f && x0f_1 <= (float)(W_-1)) ? 1.0f : 0.0f;
  float mx1_1 = (x0f_1+1.0f >= 0.0f && x0f_1+1.0f <= (float)(W_-1)) ? 1.0f : 0.0f;
  float my0_1 = (y0f_1 >= 0.0f && y0f_1 <= (float)(H_-1)) ? 1.0f : 0.0f;
  float my1_1 = (y0f_1+1.0f >= 0.0f && y0f_1+1.0f <= (float)(H_-1)) ? 1.0f : 0.0f;
  int xc0_1 = (int)fminf(fmaxf(x0f_1, 0.0f), (float)(W_-1));
  int xc1_1 = (int)fminf(fmaxf(x0f_1+1.0f, 0.0f), (float)(W_-1));
  int yc0_1 = (int)fminf(fmaxf(y0f_1, 0.0f), (float)(H_-1));
  int yc1_1 = (int)fminf(fmaxf(y0f_1+1.0f, 0.0f), (float)(H_-1));
  float w00_1 = wx0_1*wy0_1*mx0_1*my0_1;
  float w01_1 = wx1_1*wy0_1*mx1_1*my0_1;
  float w10_1 = wx0_1*wy1_1*mx0_1*my1_1;
  float w11_1 = wx1_1*wy1_1*mx1_1*my1_1;
  int base_1 = xc0_1 < (W_-2) ? xc0_1 : (W_-2);
  bool s0_1 = (xc0_1 == base_1);
  bool s1_1 = (xc1_1 == base_1 + 1);
  float wax1 = (s0_1 ? w00_1 : 0.0f) + (s1_1 ? 0.0f : w01_1);
  float way1 = (s0_1 ? 0.0f : w00_1) + (s1_1 ? w01_1 : 0.0f);
  float wbx1 = (s0_1 ? w10_1 : 0.0f) + (s1_1 ? 0.0f : w11_1);
  float wby1 = (s0_1 ? 0.0f : w10_1) + (s1_1 ? w11_1 : 0.0f);
  int rb0_1 = yc0_1*W_ + base_1;
  int rb1_1 = yc1_1*W_ + base_1;

  // ---- All 12 gathers issued back-to-back ----
  v2f a0_0 = load2(s0p + rb0_0);
  v2f b0_0 = load2(s0p + rb1_0);
  v2f a1_0 = load2(s1p + rb0_0);
  v2f b1_0 = load2(s1p + rb1_0);
  v2f a2_0 = load2(s2p + rb0_0);
  v2f b2_0 = load2(s2p + rb1_0);
  v2f a0_1 = load2(s0p + rb0_1);
  v2f b0_1 = load2(s0p + rb1_1);
  v2f a1_1 = load2(s1p + rb0_1);
  v2f b1_1 = load2(s1p + rb1_1);
  v2f a2_1 = load2(s2p + rb0_1);
  v2f b2_1 = load2(s2p + rb1_1);

  // Scheduling fence: nothing below may be hoisted above, no load may sink
  // below. Forces all 12 gathers to ISSUE before the first consumer ->
  // register allocator must keep all 24 result VGPRs live -> one incremental
  // vmcnt(11..0) wait chain instead of ~5 serialized round-trips (R2 lesson:
  // source order alone left VGPR=24, i.e. the compiler register-reused and
  // serialized the gathers).
  __builtin_amdgcn_sched_barrier(0);

  float v0_0 = a0_0.x*wax0 + a0_0.y*way0 + b0_0.x*wbx0 + b0_0.y*wby0;
  float v1_0 = a1_0.x*wax0 + a1_0.y*way0 + b1_0.x*wbx0 + b1_0.y*wby0;
  float v2_0 = a2_0.x*wax0 + a2_0.y*way0 + b2_0.x*wbx0 + b2_0.y*wby0;
  float v0_1 = a0_1.x*wax1 + a0_1.y*way1 + b0_1.x*wbx1 + b0_1.y*wby1;
  float v1_1 = a1_1.x*wax1 + a1_1.y*way1 + b1_1.x*wbx1 + b1_1.y*wby1;
  float v2_1 = a2_1.x*wax1 + a2_1.y*way1 + b2_1.x*wbx1 + b2_1.y*wby1;

  // nt stores: output is never re-read; keeps src L3-resident (R1 evidence).
  size_t op0 = (size_t)i0 * W_ + j;
  size_t op1 = op0 + W_;
  __builtin_nontemporal_store(v0_0, &out[sb + op0]);
  __builtin_nontemporal_store(v1_0, &out[sb + HW_ + op0]);
  __builtin_nontemporal_store(v2_0, &out[sb + 2*(size_t)HW_ + op0]);
  __builtin_nontemporal_store(v0_1, &out[sb + op1]);
  __builtin_nontemporal_store(v1_1, &out[sb + HW_ + op1]);
  __builtin_nontemporal_store(v2_1, &out[sb + 2*(size_t)HW_ + op1]);
}

extern "C" void kernel_launch(void* const* d_in, const int* in_sizes, int n_in,
                              void* d_out, int out_size, void* d_ws, size_t ws_size,
                              hipStream_t stream) {
  const float* src   = (const float*)d_in[0];
  const float* depth = (const float*)d_in[1];
  const float* pose  = (const float*)d_in[2];
  const float* intr  = (const float*)d_in[3];
  float* out = (float*)d_out;

  dim3 grid(NBLK_);
  warp_kernel<<<grid, 256, 0, stream>>>(src, depth, pose, intr, out);
}